// Round 4
// baseline (182.893 us; speedup 1.0000x reference)
//
#include <hip/hip_runtime.h>
#include <hip/hip_cooperative_groups.h>
#include <math.h>

namespace cg = cooperative_groups;

#define BB 32
#define CC 5
#define HH 50
#define LL 32
#define LEV 3
#define DD 256
#define KK 10
#define THRESH 0.1f
#define EPSF 1e-12f
#define RPB 8                       // rows per block in proj phase
#define NPROJ 220                   // (BB*CC + BB*HH) / RPB = 1760/8
#define NBLK 512                    // cooperative grid: 2 blocks/CU, co-residency safe
#define INNER (LL * LEV * DD)       // 24576 floats per (b,c,k)
#define INNER4 (INNER / 4)          // 6144 float4
#define CHUNKS 4
#define PERCH (INNER4 / CHUNKS)     // 1536 float4 per chunk
#define NCHUNK (BB * CC * KK * CHUNKS)  // 25600; 50 per block

typedef float f32x4 __attribute__((ext_vector_type(4)));

__global__ __launch_bounds__(256, 4)
void fused_kernel(const float* __restrict__ cdd,   // [B*C, D]
                  const float* __restrict__ his,   // [B*H, D]
                  const float* __restrict__ emb,   // [B,H, L*LEV*D]
                  const float* __restrict__ W,     // [D, D]
                  const float* __restrict__ bias,  // [D]
                  float* __restrict__ c_n,         // ws: [B*C, D]
                  float* __restrict__ h_n,         // ws: [B*H, D]
                  float* __restrict__ wv,          // ws: [B*C*K] (masked)
                  int* __restrict__ idx,           // ws: [B*C*K]
                  float* __restrict__ out)         // [B*C*K, INNER]
{
    cg::grid_group grid = cg::this_grid();
    const int bid  = blockIdx.x;
    const int j    = threadIdx.x;   // 0..255
    const int wid  = j >> 6;
    const int lane = j & 63;

    // ---------------- Phase 1: y = l2norm(x @ W + b), 8 rows per block ----------------
    if (bid < NPROJ) {
        const int row0 = bid * RPB;

        __shared__ float xs[RPB][DD];
        #pragma unroll
        for (int r = 0; r < RPB; ++r) {
            const int row = row0 + r;
            const float* x = (row < BB * CC) ? (cdd + (size_t)row * DD)
                                             : (his + (size_t)(row - BB * CC) * DD);
            xs[r][j] = x[j];
        }
        __syncthreads();

        const float bj = bias[j];
        float acc[RPB];
        #pragma unroll
        for (int r = 0; r < RPB; ++r) acc[r] = bj;

        for (int d = 0; d < DD; d += 4) {
            const float w0 = W[(size_t)(d + 0) * DD + j];   // coalesced, L2-hit
            const float w1 = W[(size_t)(d + 1) * DD + j];
            const float w2 = W[(size_t)(d + 2) * DD + j];
            const float w3 = W[(size_t)(d + 3) * DD + j];
            #pragma unroll
            for (int r = 0; r < RPB; ++r) {
                const float4 xv = *(const float4*)&xs[r][d];   // LDS broadcast
                acc[r] = fmaf(xv.x, w0, fmaf(xv.y, w1, fmaf(xv.z, w2, fmaf(xv.w, w3, acc[r]))));
            }
        }

        __shared__ float part[RPB][4];
        #pragma unroll
        for (int r = 0; r < RPB; ++r) {
            float s = acc[r] * acc[r];
            #pragma unroll
            for (int off = 32; off > 0; off >>= 1) s += __shfl_xor(s, off, 64);
            if (lane == 0) part[r][wid] = s;
        }
        __syncthreads();
        __shared__ float inv_s[RPB];
        if (j < RPB) {
            const float s = part[j][0] + part[j][1] + part[j][2] + part[j][3];
            inv_s[j] = 1.0f / fmaxf(sqrtf(s), EPSF);
        }
        __syncthreads();

        #pragma unroll
        for (int r = 0; r < RPB; ++r) {
            const int row = row0 + r;
            float* y = (row < BB * CC) ? (c_n + (size_t)row * DD)
                                       : (h_n + (size_t)(row - BB * CC) * DD);
            y[j] = acc[r] * inv_s[r];
        }
    }

    grid.sync();

    // ---------------- Phase 2: attn + wave-parallel top-K per (b,c) ----------------
    if (bid < BB * CC) {
        const int bc = bid;
        const int b  = bc / CC;

        __shared__ float cs[DD];
        __shared__ float attn_s[64];
        cs[j] = c_n[(size_t)bc * DD + j];
        if (j < 64) attn_s[j] = -INFINITY;
        __syncthreads();

        for (int h = wid; h < HH; h += 4) {
            const float* hr = h_n + (size_t)(b * HH + h) * DD;
            float p = 0.f;
            #pragma unroll
            for (int i = 0; i < 4; ++i) p += cs[lane + i * 64] * hr[lane + i * 64];
            #pragma unroll
            for (int off = 32; off > 0; off >>= 1) p += __shfl_down(p, off, 64);
            if (lane == 0) attn_s[h] = p;
        }
        __syncthreads();

        if (wid == 0) {  // 10 rounds of butterfly argmax (tie -> lowest index = lax.top_k)
            float v   = attn_s[lane];   // lanes 50..63 hold -inf
            int   myi = lane;
            for (int k = 0; k < KK; ++k) {
                float bv = v;
                int   bi = myi;
                #pragma unroll
                for (int off = 32; off > 0; off >>= 1) {
                    const float ov = __shfl_xor(bv, off, 64);
                    const int   oi = __shfl_xor(bi, off, 64);
                    if (ov > bv || (ov == bv && oi < bi)) { bv = ov; bi = oi; }
                }
                if (lane == 0) {
                    wv[bc * KK + k]  = (bv < THRESH) ? 0.0f : bv;
                    idx[bc * KK + k] = bi;
                }
                if (myi == bi) v = -INFINITY;
            }
        }
    }

    grid.sync();

    // ---------------- Phase 3: gather + scale, grid-stride over 24 KB chunks ----------------
    for (int g = bid; g < NCHUNK; g += NBLK) {
        const int blk   = g >> 2;        // (b,c,k)
        const int chunk = g & 3;
        const int b     = blk / (CC * KK);

        const float w_ = wv[blk];
        const int   hi = idx[blk];

        f32x4* dst = (f32x4*)(out + (size_t)blk * INNER) + (size_t)chunk * PERCH;

        if (w_ == 0.0f) {
            const f32x4 z = (f32x4){0.f, 0.f, 0.f, 0.f};
            #pragma unroll
            for (int u = 0; u < PERCH / 256; ++u)
                dst[j + 256 * u] = z;
        } else {
            const f32x4* src = (const f32x4*)(emb + (size_t)(b * HH + hi) * INNER)
                               + (size_t)chunk * PERCH;
            #pragma unroll
            for (int u = 0; u < PERCH / 256; ++u)
                dst[j + 256 * u] = src[j + 256 * u] * w_;
        }
    }
}

extern "C" void kernel_launch(void* const* d_in, const int* in_sizes, int n_in,
                              void* d_out, int out_size, void* d_ws, size_t ws_size,
                              hipStream_t stream) {
    const float* cdd  = (const float*)d_in[0];   // [B,C,D]
    const float* his  = (const float*)d_in[1];   // [B,H,D]
    const float* emb  = (const float*)d_in[2];   // [B,H,L,LEV,D]
    const float* W    = (const float*)d_in[3];   // [D,D]
    const float* bias = (const float*)d_in[4];   // [D]
    float* out = (float*)d_out;

    // workspace layout
    char* ws = (char*)d_ws;
    float* c_n = (float*)ws;                               // B*C*D floats = 163840 B
    float* h_n = (float*)(ws + 163840);                    // B*H*D floats = 1638400 B
    float* wvp = (float*)(ws + 163840 + 1638400);          // B*C*K floats = 6400 B
    int*   idp = (int*)  (ws + 163840 + 1638400 + 6400);   // B*C*K ints   = 6400 B

    void* args[] = { (void*)&cdd, (void*)&his, (void*)&emb, (void*)&W, (void*)&bias,
                     (void*)&c_n, (void*)&h_n, (void*)&wvp, (void*)&idp, (void*)&out };
    hipLaunchCooperativeKernel((const void*)fused_kernel,
                               dim3(NBLK), dim3(256), args, 0, stream);
}

// Round 5
// 93.343 us; speedup vs baseline: 1.9594x; 1.9594x over previous
//
#include <hip/hip_runtime.h>
#include <math.h>

#define BB 32
#define CC 5
#define HH 50
#define LL 32
#define LEV 3
#define DD 256
#define KK 10
#define THRESH 0.1f
#define EPSF 1e-12f
#define RPB 4                      // rows per block in proj kernel
#define NPROJ ((BB * CC + BB * HH) / RPB)   // 440 blocks
#define INNER (LL * LEV * DD)      // 24576 floats per (b,c,k)
#define INNER4 (INNER / 4)         // 6144 float4
#define CHUNKS 4
#define PERCH (INNER4 / CHUNKS)    // 1536 float4 per chunk (6 per thread @256)

typedef float f32x4 __attribute__((ext_vector_type(4)));

// ---------------- Kernel 1: y = l2norm(x @ W + b), 4 rows per block (440 blocks).
__global__ void proj_norm_kernel(const float* __restrict__ cdd,
                                 const float* __restrict__ his,
                                 const float* __restrict__ W,
                                 const float* __restrict__ bias,
                                 float* __restrict__ c_out,   // [B*C, D]
                                 float* __restrict__ h_out)   // [B*H, D]
{
    const int row0 = blockIdx.x * RPB;
    const int j    = threadIdx.x;     // 0..255
    const int wid  = j >> 6;
    const int lane = j & 63;

    __shared__ float xs[RPB][DD];
    #pragma unroll
    for (int r = 0; r < RPB; ++r) {
        const int row = row0 + r;
        const float* x = (row < BB * CC) ? (cdd + (size_t)row * DD)
                                         : (his + (size_t)(row - BB * CC) * DD);
        xs[r][j] = x[j];
    }
    __syncthreads();

    const float bj = bias[j];
    float acc[RPB];
    #pragma unroll
    for (int r = 0; r < RPB; ++r) acc[r] = bj;

    for (int d = 0; d < DD; d += 4) {
        const float w0 = W[(size_t)(d + 0) * DD + j];   // coalesced across j, L2-hit
        const float w1 = W[(size_t)(d + 1) * DD + j];
        const float w2 = W[(size_t)(d + 2) * DD + j];
        const float w3 = W[(size_t)(d + 3) * DD + j];
        #pragma unroll
        for (int r = 0; r < RPB; ++r) {
            const float4 xv = *(const float4*)&xs[r][d];   // LDS broadcast
            acc[r] = fmaf(xv.x, w0, fmaf(xv.y, w1, fmaf(xv.z, w2, fmaf(xv.w, w3, acc[r]))));
        }
    }

    // per-row sum of squares: wave shuffle reduce, then 4 wave-partials via LDS
    __shared__ float part[RPB][4];
    #pragma unroll
    for (int r = 0; r < RPB; ++r) {
        float s = acc[r] * acc[r];
        #pragma unroll
        for (int off = 32; off > 0; off >>= 1) s += __shfl_xor(s, off, 64);
        if (lane == 0) part[r][wid] = s;
    }
    __syncthreads();
    __shared__ float inv_s[RPB];
    if (j < RPB) {
        const float s = part[j][0] + part[j][1] + part[j][2] + part[j][3];
        inv_s[j] = 1.0f / fmaxf(sqrtf(s), EPSF);
    }
    __syncthreads();

    #pragma unroll
    for (int r = 0; r < RPB; ++r) {
        const int row = row0 + r;
        float* y = (row < BB * CC) ? (c_out + (size_t)row * DD)
                                   : (h_out + (size_t)(row - BB * CC) * DD);
        y[j] = acc[r] * inv_s[r];
    }
}

// ---------------- Kernel 2: attn + wave-parallel top-K per (b,c).
// Writes packed (w, idx-bits) float2 so the gather does ONE dependent load.
__global__ void attn_topk_kernel(const float* __restrict__ c_n,   // [B*C, D]
                                 const float* __restrict__ h_n,   // [B*H, D]
                                 float2* __restrict__ wvidx)      // [B*C*K]
{
    const int bc   = blockIdx.x;     // 0..159
    const int b    = bc / CC;
    const int tid  = threadIdx.x;    // 0..255
    const int wid  = tid >> 6;
    const int lane = tid & 63;

    __shared__ float cs[DD];
    __shared__ float attn_s[64];
    cs[tid] = c_n[(size_t)bc * DD + tid];
    if (tid < 64) attn_s[tid] = -INFINITY;
    __syncthreads();

    for (int h = wid; h < HH; h += 4) {
        const float* hr = h_n + (size_t)(b * HH + h) * DD;
        float p = 0.f;
        #pragma unroll
        for (int i = 0; i < 4; ++i) p += cs[lane + i * 64] * hr[lane + i * 64];
        #pragma unroll
        for (int off = 32; off > 0; off >>= 1) p += __shfl_down(p, off, 64);
        if (lane == 0) attn_s[h] = p;
    }
    __syncthreads();

    // wave 0: 10 rounds of butterfly argmax (tie -> lowest index, = lax.top_k)
    if (wid == 0) {
        float v   = attn_s[lane];    // lanes 50..63 hold -inf
        int   myi = lane;
        for (int k = 0; k < KK; ++k) {
            float bv = v;
            int   bi = myi;
            #pragma unroll
            for (int off = 32; off > 0; off >>= 1) {
                const float ov = __shfl_xor(bv, off, 64);
                const int   oi = __shfl_xor(bi, off, 64);
                if (ov > bv || (ov == bv && oi < bi)) { bv = ov; bi = oi; }
            }
            if (lane == 0)
                wvidx[bc * KK + k] = make_float2((bv < THRESH) ? 0.0f : bv,
                                                 __int_as_float(bi));
            if (myi == bi) v = -INFINITY;   // remove winner
        }
    }
}

// ---------------- Kernel 3: out[b,c,k,:] = emb[b, idx, :] * w
// Batched: 6 loads into registers, then 6 NT stores -> 6 loads always in flight.
__global__ __launch_bounds__(256)
void gather_scale_kernel(const float* __restrict__ emb,     // [B,H, INNER]
                         const float2* __restrict__ wvidx,  // [B*C*K]
                         float* __restrict__ out)
{
    const int g     = blockIdx.x;    // 0 .. B*C*K*CHUNKS-1
    const int blk   = g >> 2;        // (b,c,k)
    const int chunk = g & 3;
    const int b     = blk / (CC * KK);

    const float2 wi = wvidx[blk];    // one 8B dependent load per block
    const float  w_ = wi.x;

    f32x4* dst = (f32x4*)(out + (size_t)blk * INNER) + chunk * PERCH + threadIdx.x;

    if (w_ == 0.0f) {
        const f32x4 z = (f32x4){0.f, 0.f, 0.f, 0.f};
        #pragma unroll
        for (int u = 0; u < PERCH / 256; ++u)
            __builtin_nontemporal_store(z, dst + 256 * u);
    } else {
        const int hi = __float_as_int(wi.y);
        const f32x4* src = (const f32x4*)(emb + (size_t)(b * HH + hi) * INNER)
                           + chunk * PERCH + threadIdx.x;
        f32x4 v[PERCH / 256];
        #pragma unroll
        for (int u = 0; u < PERCH / 256; ++u)   // all 6 loads issued first
            v[u] = src[256 * u];
        #pragma unroll
        for (int u = 0; u < PERCH / 256; ++u)
            __builtin_nontemporal_store(v[u] * w_, dst + 256 * u);
    }
}

extern "C" void kernel_launch(void* const* d_in, const int* in_sizes, int n_in,
                              void* d_out, int out_size, void* d_ws, size_t ws_size,
                              hipStream_t stream) {
    const float* cdd  = (const float*)d_in[0];   // [B,C,D]
    const float* his  = (const float*)d_in[1];   // [B,H,D]
    const float* emb  = (const float*)d_in[2];   // [B,H,L,LEV,D]
    const float* W    = (const float*)d_in[3];   // [D,D]
    const float* bias = (const float*)d_in[4];   // [D]
    float* out = (float*)d_out;

    // workspace layout
    char* ws = (char*)d_ws;
    float*  c_n   = (float*)ws;                              // B*C*D floats = 163840 B
    float*  h_n   = (float*)(ws + 163840);                   // B*H*D floats = 1638400 B
    float2* wvidx = (float2*)(ws + 163840 + 1638400);        // B*C*K float2 = 12800 B (8B-aligned)

    proj_norm_kernel<<<NPROJ, DD, 0, stream>>>(cdd, his, W, bias, c_n, h_n);
    attn_topk_kernel<<<BB * CC, DD, 0, stream>>>(c_n, h_n, wvidx);
    gather_scale_kernel<<<BB * CC * KK * CHUNKS, 256, 0, stream>>>(emb, wvidx, out);
}

// Round 6
// 81.492 us; speedup vs baseline: 2.2443x; 1.1454x over previous
//
#include <hip/hip_runtime.h>
#include <math.h>

#define BB 32
#define CC 5
#define HH 50
#define LL 32
#define LEV 3
#define DD 256
#define KK 10
#define THRESH 0.1f
#define EPSF 1e-12f
#define RPB 8                      // rows per block in proj kernel
#define NPROJ ((BB * CC + BB * HH) / RPB)   // 220 blocks
#define INNER (LL * LEV * DD)      // 24576 floats per (b,c,k)
#define INNER4 (INNER / 4)         // 6144 float4 per (b,c,k)
#define NBCK (BB * CC * KK)        // 1600 output rows
#define TOTAL4 (NBCK * INNER4)     // 9,830,400 float4 total
#define NGBLK 2048                 // gather grid: 8 blocks/CU

typedef float f32x4 __attribute__((ext_vector_type(4)));

// ---------------- Kernel 1: y = l2norm(x @ W + b), 8 rows per block.
__global__ void proj_norm_kernel(const float* __restrict__ cdd,
                                 const float* __restrict__ his,
                                 const float* __restrict__ W,
                                 const float* __restrict__ bias,
                                 float* __restrict__ c_out,   // [B*C, D]
                                 float* __restrict__ h_out)   // [B*H, D]
{
    const int row0 = blockIdx.x * RPB;
    const int j    = threadIdx.x;     // 0..255
    const int wid  = j >> 6;
    const int lane = j & 63;

    __shared__ float xs[RPB][DD];
    #pragma unroll
    for (int r = 0; r < RPB; ++r) {
        const int row = row0 + r;
        const float* x = (row < BB * CC) ? (cdd + (size_t)row * DD)
                                         : (his + (size_t)(row - BB * CC) * DD);
        xs[r][j] = x[j];
    }
    __syncthreads();

    const float bj = bias[j];
    float acc[RPB];
    #pragma unroll
    for (int r = 0; r < RPB; ++r) acc[r] = bj;

    for (int d = 0; d < DD; d += 4) {
        const float w0 = W[(size_t)(d + 0) * DD + j];   // coalesced across j, L2-hit
        const float w1 = W[(size_t)(d + 1) * DD + j];
        const float w2 = W[(size_t)(d + 2) * DD + j];
        const float w3 = W[(size_t)(d + 3) * DD + j];
        #pragma unroll
        for (int r = 0; r < RPB; ++r) {
            const float4 xv = *(const float4*)&xs[r][d];   // LDS broadcast
            acc[r] = fmaf(xv.x, w0, fmaf(xv.y, w1, fmaf(xv.z, w2, fmaf(xv.w, w3, acc[r]))));
        }
    }

    // per-row sum of squares: wave shuffle reduce, then 4 wave-partials via LDS
    __shared__ float part[RPB][4];
    #pragma unroll
    for (int r = 0; r < RPB; ++r) {
        float s = acc[r] * acc[r];
        #pragma unroll
        for (int off = 32; off > 0; off >>= 1) s += __shfl_xor(s, off, 64);
        if (lane == 0) part[r][wid] = s;
    }
    __syncthreads();
    __shared__ float inv_s[RPB];
    if (j < RPB) {
        const float s = part[j][0] + part[j][1] + part[j][2] + part[j][3];
        inv_s[j] = 1.0f / fmaxf(sqrtf(s), EPSF);
    }
    __syncthreads();

    #pragma unroll
    for (int r = 0; r < RPB; ++r) {
        const int row = row0 + r;
        float* y = (row < BB * CC) ? (c_out + (size_t)row * DD)
                                   : (h_out + (size_t)(row - BB * CC) * DD);
        y[j] = acc[r] * inv_s[r];
    }
}

// ---------------- Kernel 2: attn + wave-parallel top-K per (b,c).
// Writes packed (w, idx-bits) float2.
__global__ void attn_topk_kernel(const float* __restrict__ c_n,   // [B*C, D]
                                 const float* __restrict__ h_n,   // [B*H, D]
                                 float2* __restrict__ wvidx)      // [B*C*K]
{
    const int bc   = blockIdx.x;     // 0..159
    const int b    = bc / CC;
    const int tid  = threadIdx.x;    // 0..255
    const int wid  = tid >> 6;
    const int lane = tid & 63;

    __shared__ float cs[DD];
    __shared__ float attn_s[64];
    cs[tid] = c_n[(size_t)bc * DD + tid];
    if (tid < 64) attn_s[tid] = -INFINITY;
    __syncthreads();

    for (int h = wid; h < HH; h += 4) {
        const float* hr = h_n + (size_t)(b * HH + h) * DD;
        float p = 0.f;
        #pragma unroll
        for (int i = 0; i < 4; ++i) p += cs[lane + i * 64] * hr[lane + i * 64];
        #pragma unroll
        for (int off = 32; off > 0; off >>= 1) p += __shfl_down(p, off, 64);
        if (lane == 0) attn_s[h] = p;
    }
    __syncthreads();

    // wave 0: 10 rounds of butterfly argmax (tie -> lowest index, = lax.top_k)
    if (wid == 0) {
        float v   = attn_s[lane];    // lanes 50..63 hold -inf
        int   myi = lane;
        for (int k = 0; k < KK; ++k) {
            float bv = v;
            int   bi = myi;
            #pragma unroll
            for (int off = 32; off > 0; off >>= 1) {
                const float ov = __shfl_xor(bv, off, 64);
                const int   oi = __shfl_xor(bi, off, 64);
                if (ov > bv || (ov == bv && oi < bi)) { bv = ov; bi = oi; }
            }
            if (lane == 0)
                wvidx[bc * KK + k] = make_float2((bv < THRESH) ? 0.0f : bv,
                                                 __int_as_float(bi));
            if (myi == bi) v = -INFINITY;   // remove winner
        }
    }
}

// ---------------- Kernel 3: flat grid-stride gather+scale.
// out viewed as TOTAL4 float4 elements; element i belongs to row blk=i/6144.
// (w,idx) table cached in LDS (12.8 KB); long-lived blocks, no per-row prologue.
__global__ __launch_bounds__(256)
void gather_flat_kernel(const float* __restrict__ emb,     // [B,H, INNER]
                        const float2* __restrict__ wvidx,  // [NBCK]
                        float* __restrict__ out)
{
    __shared__ float2 tbl[NBCK];     // 1600 * 8B = 12.8 KB
    for (int t = threadIdx.x; t < NBCK; t += 256)
        tbl[t] = wvidx[t];
    __syncthreads();

    const f32x4* __restrict__ src4 = (const f32x4*)emb;
    f32x4* __restrict__ dst4       = (f32x4*)out;

    const unsigned stride = NGBLK * 256;
    for (unsigned i = blockIdx.x * 256 + threadIdx.x; i < TOTAL4; i += stride) {
        const unsigned blk = i / INNER4;           // magic-div (const divisor)
        const unsigned o4  = i - blk * INNER4;
        const float2   wi  = tbl[blk];             // LDS broadcast (lanes share blk)

        if (wi.x == 0.0f) {
            __builtin_nontemporal_store((f32x4){0.f, 0.f, 0.f, 0.f}, dst4 + i);
        } else {
            const unsigned b  = blk / (CC * KK);
            const unsigned hi = __float_as_uint(wi.y);
            const f32x4 v = src4[(size_t)(b * HH + hi) * INNER4 + o4];
            __builtin_nontemporal_store(v * wi.x, dst4 + i);
        }
    }
}

extern "C" void kernel_launch(void* const* d_in, const int* in_sizes, int n_in,
                              void* d_out, int out_size, void* d_ws, size_t ws_size,
                              hipStream_t stream) {
    const float* cdd  = (const float*)d_in[0];   // [B,C,D]
    const float* his  = (const float*)d_in[1];   // [B,H,D]
    const float* emb  = (const float*)d_in[2];   // [B,H,L,LEV,D]
    const float* W    = (const float*)d_in[3];   // [D,D]
    const float* bias = (const float*)d_in[4];   // [D]
    float* out = (float*)d_out;

    // workspace layout
    char* ws = (char*)d_ws;
    float*  c_n   = (float*)ws;                              // B*C*D floats = 163840 B
    float*  h_n   = (float*)(ws + 163840);                   // B*H*D floats = 1638400 B
    float2* wvidx = (float2*)(ws + 163840 + 1638400);        // NBCK float2  = 12800 B

    proj_norm_kernel<<<NPROJ, DD, 0, stream>>>(cdd, his, W, bias, c_n, h_n);
    attn_topk_kernel<<<BB * CC, DD, 0, stream>>>(c_n, h_n, wvidx);
    gather_flat_kernel<<<NGBLK, 256, 0, stream>>>(emb, wvidx, out);
}